// Round 11
// baseline (129.247 us; speedup 1.0000x reference)
//
#include <hip/hip_runtime.h>
#include <hip/hip_bf16.h>
#include <math.h>

#define Bq   2048
#define Cq   8
#define Dq   768
#define NROW 16384      // B*C per half
#define NTOT 32768      // 2*B*C
#define Nq   4096       // 2*B rows of f
#define TEMPq 0.07f
#define NKC  96         // 768/8 k-chunks of 8 bf16 (16 B)

typedef __attribute__((ext_vector_type(8))) short bf16x8;
typedef __attribute__((ext_vector_type(4))) float f32x4;
typedef __attribute__((ext_vector_type(8))) _Float16 f16x8;

// persistent device scratch (fully overwritten every call -> deterministic)
__device__ __hip_bfloat16 g_pooledb[(size_t)Nq * Dq];
__device__ __hip_bfloat16 g_Wb[(size_t)Dq * Dq];
__device__ float          g_f[(size_t)Nq * Dq];
__device__ short          g_fbt[(size_t)NKC * Nq * 8];   // [kc][row][8 bf16] chunk-transposed
__device__ _Float16       g_simh[(size_t)Nq * Nq];
__device__ unsigned int   g_viol;
__device__ float          g_rowloss[Nq];

#define GLDS16(src, dst) __builtin_amdgcn_global_load_lds( \
    (const __attribute__((address_space(1))) void*)(src),  \
    (__attribute__((address_space(3))) void*)(dst), 16, 0, 0)

// ---------- merged: [blocks 0..1023] fused pool, [1024..1599] W->bf16 ----------
__global__ __launch_bounds__(256) void prep_kernel(const float* __restrict__ z,
                                                   const float* __restrict__ query,
                                                   const float* __restrict__ attn_temp,
                                                   const float* __restrict__ W) {
    if (blockIdx.x >= 1024) {
        int i = (blockIdx.x - 1024) * 256 + threadIdx.x;
        if (i == 0) g_viol = 0u;
        float4 v = ((const float4*)W)[i];
        short4 o;
        o.x = ((__hip_bfloat16_raw)__float2bfloat16(v.x)).x;
        o.y = ((__hip_bfloat16_raw)__float2bfloat16(v.y)).x;
        o.z = ((__hip_bfloat16_raw)__float2bfloat16(v.z)).x;
        o.w = ((__hip_bfloat16_raw)__float2bfloat16(v.w)).x;
        ((short4*)g_Wb)[i] = o;
        return;
    }
    int seg  = (int)((blockIdx.x * blockDim.x + threadIdx.x) >> 6);
    int lane = threadIdx.x & 63;
    if (seg >= Nq) return;
    int half = seg >> 11;
    int b    = seg & 2047;
    int baseRow = half * NROW + b * Cq;
    float invt = 1.f / attn_temp[0];

    float4 q4[3];
#pragma unroll
    for (int j = 0; j < 3; ++j) q4[j] = *(const float4*)(query + j * 256 + lane * 4);

    float4 v4[Cq][3];
    float s[Cq];
#pragma unroll
    for (int c = 0; c < Cq; ++c) {
        const float* zr = z + (size_t)(baseRow + c) * Dq;
        float acc = 0.f;
#pragma unroll
        for (int j = 0; j < 3; ++j) {
            float4 vz = *(const float4*)(zr + j * 256 + lane * 4);
            v4[c][j] = vz;
            acc += vz.x * q4[j].x + vz.y * q4[j].y + vz.z * q4[j].z + vz.w * q4[j].w;
        }
#pragma unroll
        for (int o = 32; o > 0; o >>= 1) acc += __shfl_xor(acc, o, 64);
        s[c] = acc * invt;
    }
    float m = s[0];
#pragma unroll
    for (int c = 1; c < Cq; ++c) m = fmaxf(m, s[c]);
    float e[Cq], denom = 0.f;
#pragma unroll
    for (int c = 0; c < Cq; ++c) { e[c] = expf(s[c] - m); denom += e[c]; }
    float inv = 1.f / (denom + 1e-8f);
#pragma unroll
    for (int j = 0; j < 3; ++j) {
        float4 acc = {0.f, 0.f, 0.f, 0.f};
#pragma unroll
        for (int c = 0; c < Cq; ++c) {
            acc.x += v4[c][j].x * e[c];
            acc.y += v4[c][j].y * e[c];
            acc.z += v4[c][j].z * e[c];
            acc.w += v4[c][j].w * e[c];
        }
        short4 o;
        o.x = ((__hip_bfloat16_raw)__float2bfloat16(acc.x * inv)).x;
        o.y = ((__hip_bfloat16_raw)__float2bfloat16(acc.y * inv)).x;
        o.z = ((__hip_bfloat16_raw)__float2bfloat16(acc.z * inv)).x;
        o.w = ((__hip_bfloat16_raw)__float2bfloat16(acc.w * inv)).x;
        *(short4*)((short*)g_pooledb + (size_t)seg * Dq + j * 256 + lane * 4) = o;
    }
}

// ---------- f = pooled @ W^T + b via bf16 MFMA (M=4096, N=768, K=768) ----------
__global__ __launch_bounds__(256) void fw_mfma_kernel(const float* __restrict__ bias) {
    __shared__ short lA[128 * 32];
    __shared__ short lB[128 * 32];
    const int bm = blockIdx.y * 128;
    const int bn = blockIdx.x * 128;

    const int tid  = threadIdx.x;
    const int wave = tid >> 6, lane = tid & 63;
    const int wr = wave >> 1, wc = wave & 1;

    const short* A = (const short*)g_pooledb;
    const short* Bt = (const short*)g_Wb;

    const int c0 = wave * 2, c1 = wave * 2 + 1;
    const int srow = lane >> 2;
    const int scol = (lane & 3) * 8;

    f32x4 acc[4][4];
#pragma unroll
    for (int m = 0; m < 4; ++m)
#pragma unroll
        for (int n = 0; n < 4; ++n) acc[m][n] = (f32x4){0.f, 0.f, 0.f, 0.f};

    for (int k0 = 0; k0 < Dq; k0 += 32) {
        GLDS16(A  + (size_t)(bm + c0 * 16 + srow) * Dq + k0 + scol, lA + c0 * 512);
        GLDS16(A  + (size_t)(bm + c1 * 16 + srow) * Dq + k0 + scol, lA + c1 * 512);
        GLDS16(Bt + (size_t)(bn + c0 * 16 + srow) * Dq + k0 + scol, lB + c0 * 512);
        GLDS16(Bt + (size_t)(bn + c1 * 16 + srow) * Dq + k0 + scol, lB + c1 * 512);
        __syncthreads();

        bf16x8 af[4], bfr[4];
#pragma unroll
        for (int m = 0; m < 4; ++m) {
            int row = wr * 64 + m * 16 + (lane & 15);
            af[m] = *(const bf16x8*)(lA + row * 32 + (lane >> 4) * 8);
        }
#pragma unroll
        for (int n = 0; n < 4; ++n) {
            int row = wc * 64 + n * 16 + (lane & 15);
            bfr[n] = *(const bf16x8*)(lB + row * 32 + (lane >> 4) * 8);
        }
#pragma unroll
        for (int m = 0; m < 4; ++m)
#pragma unroll
            for (int n = 0; n < 4; ++n)
                acc[m][n] = __builtin_amdgcn_mfma_f32_16x16x32_bf16(af[m], bfr[n], acc[m][n], 0, 0, 0);
        __syncthreads();
    }

#pragma unroll
    for (int m = 0; m < 4; ++m) {
        int rowb = bm + wr * 64 + m * 16 + (lane >> 4) * 4;
#pragma unroll
        for (int n = 0; n < 4; ++n) {
            int col = bn + wc * 64 + n * 16 + (lane & 15);
            float bc = bias[col];
#pragma unroll
            for (int j = 0; j < 4; ++j)
                g_f[(size_t)(rowb + j) * Dq + col] = acc[m][n][j] + bc;
        }
    }
}

// ---------- row-normalize -> bf16, chunk-transposed store. 16 rows/block ----------
__global__ __launch_bounds__(256) void normalize_kernel() {
    __shared__ short rowbuf[16][776];
    const int tid = threadIdx.x;
    const int wave = tid >> 6, lane = tid & 63;
    const int r0 = blockIdx.x * 16;

    for (int rr = wave; rr < 16; rr += 4) {
        int row = r0 + rr;
        float v[12];
        float ss = 0.f;
#pragma unroll
        for (int j = 0; j < 12; ++j) { v[j] = g_f[(size_t)row * Dq + j * 64 + lane]; ss += v[j] * v[j]; }
#pragma unroll
        for (int o = 32; o > 0; o >>= 1) ss += __shfl_xor(ss, o, 64);
        float rn = 1.f / sqrtf(ss);
#pragma unroll
        for (int j = 0; j < 12; ++j)
            rowbuf[rr][j * 64 + lane] = ((__hip_bfloat16_raw)__float2bfloat16(v[j] * rn)).x;
    }
    __syncthreads();
#pragma unroll
    for (int i = 0; i < 6; ++i) {
        int idx = i * 256 + tid;
        int ch = idx >> 4;
        int r  = idx & 15;
        bf16x8 val = *(const bf16x8*)&rowbuf[r][ch * 8];
        *(bf16x8*)&g_fbt[((size_t)ch * Nq + r0 + r) * 8] = val;
    }
}

// ---------- sim = fb @ fb^T : 256^2 tile, 8 waves, BK=64, dbuf + counted vmcnt ----------
// Epilogue: round-8 style direct fp16 stores (the LDS-bounce A/B showed a regression).
#define STAGE_SIM(b, kt_) do {                                                          \
    _Pragma("unroll")                                                                   \
    for (int i = 0; i < 4; ++i) {                                                       \
        GLDS16(fbt + ((size_t)((kt_) * 8 + wave) * Nq + bm + i * 64 + lane) * 8,        \
               As + ((b) * 2048 + wave * 256 + i * 64) * 8);                            \
        GLDS16(fbt + ((size_t)((kt_) * 8 + wave) * Nq + bn + i * 64 + lane) * 8,        \
               Bs + ((b) * 2048 + wave * 256 + i * 64) * 8);                            \
    }                                                                                   \
} while (0)

__global__ __launch_bounds__(512) void sim_mfma_kernel() {
    extern __shared__ short smem[];          // 128 KiB
    short* As = smem;
    short* Bs = smem + 32768;

    const int tid  = threadIdx.x;
    const int wave = tid >> 6, lane = tid & 63;
    const int wm = wave >> 2, wn = wave & 3;
    const int bm = blockIdx.y * 256, bn = blockIdx.x * 256;
    const short* fbt = g_fbt;

    f32x4 acc[8][4];
#pragma unroll
    for (int mi = 0; mi < 8; ++mi)
#pragma unroll
        for (int ni = 0; ni < 4; ++ni) acc[mi][ni] = (f32x4){0.f, 0.f, 0.f, 0.f};

    STAGE_SIM(0, 0);

#pragma unroll 1
    for (int kt = 0; kt < 12; ++kt) {
        const int cur = kt & 1;
        if (kt < 11) {
            STAGE_SIM(cur ^ 1, kt + 1);
            asm volatile("s_waitcnt vmcnt(8)" ::: "memory");
        } else {
            asm volatile("s_waitcnt vmcnt(0)" ::: "memory");
        }
        __builtin_amdgcn_s_barrier();
        __builtin_amdgcn_sched_barrier(0);

#pragma unroll
        for (int ks = 0; ks < 2; ++ks) {
            bf16x8 af[8], bfr[4];
            const int kc = (ks * 4 + (lane >> 4)) * 256;
#pragma unroll
            for (int mi = 0; mi < 8; ++mi)
                af[mi] = *(const bf16x8*)(As + (cur * 2048 + kc + wm * 128 + mi * 16 + (lane & 15)) * 8);
#pragma unroll
            for (int ni = 0; ni < 4; ++ni)
                bfr[ni] = *(const bf16x8*)(Bs + (cur * 2048 + kc + wn * 64 + ni * 16 + (lane & 15)) * 8);
            __builtin_amdgcn_s_setprio(1);
#pragma unroll
            for (int mi = 0; mi < 8; ++mi)
#pragma unroll
                for (int ni = 0; ni < 4; ++ni)
                    acc[mi][ni] = __builtin_amdgcn_mfma_f32_16x16x32_bf16(af[mi], bfr[ni], acc[mi][ni], 0, 0, 0);
            __builtin_amdgcn_s_setprio(0);
        }
        __builtin_amdgcn_sched_barrier(0);
        __builtin_amdgcn_s_barrier();
    }

    // epilogue: direct fp16 store + violation count (round-8 measured-good path)
    int vio = 0;
#pragma unroll
    for (int mi = 0; mi < 8; ++mi) {
        int rowb = bm + wm * 128 + mi * 16 + (lane >> 4) * 4;
#pragma unroll
        for (int ni = 0; ni < 4; ++ni) {
            int col = bn + wn * 64 + ni * 16 + (lane & 15);
#pragma unroll
            for (int j = 0; j < 4; ++j) {
                float x = acc[mi][ni][j];
                g_simh[(size_t)(rowb + j) * Nq + col] = (_Float16)x;
                vio += (x > 0.9f) && ((((rowb + j) ^ col) & 2047) != 0);
            }
        }
    }
#pragma unroll
    for (int o = 32; o > 0; o >>= 1) vio += __shfl_xor(vio, o, 64);
    if (lane == 0 && vio > 0) atomicAdd(&g_viol, (unsigned int)vio);
}

// ---------- per-row top-k logsumexp: one wave/row, values kept in fp16 regs (16 VGPR) ----------
__global__ __launch_bounds__(256) void lse_kernel() {
    const int row_id = (int)((blockIdx.x * blockDim.x + threadIdx.x) >> 6);
    const int lane = threadIdx.x & 63;
    const _Float16* row = g_simh + (size_t)row_id * Nq;
    const int labi = row_id & 2047;
    const float invT = 1.0f / TEMPq;

    long long total = (long long)Nq * 4094LL - (long long)g_viol;
    int k = (int)(total / 8192LL);
    if (k < 1) k = 1;

    // 64 values/lane in 8 x f16x8 (16 VGPRs); unsafe slots -> fp16 sentinel -2.0
    f16x8 xv[8];
    float mx = -1e30f, mn = 1e30f;
    int cnt = 0;
    const _Float16 SENT = (_Float16)(-2.0f);
#pragma unroll
    for (int q = 0; q < 8; ++q) {
        int j0 = q * 512 + lane * 8;
        f16x8 x8 = *(const f16x8*)(row + j0);
#pragma unroll
        for (int s = 0; s < 8; ++s) {
            int j = j0 + s;
            float x = (float)x8[s];
            bool sf = (x <= 0.9f) && (((j ^ labi) & 2047) != 0);
            if (sf) { mx = fmaxf(mx, x); mn = fminf(mn, x); }
            else x8[s] = SENT;
            cnt += (int)__popcll(__ballot(sf));
        }
        xv[q] = x8;
    }
#pragma unroll
    for (int o = 32; o > 0; o >>= 1) {
        mx = fmaxf(mx, __shfl_xor(mx, o, 64));
        mn = fminf(mn, __shfl_xor(mn, o, 64));
    }

    const float pos = (float)row[(row_id + Bq) & (Nq - 1)];
    const float mxs = (cnt > 0) ? mx : -10.0f;
    const float ml  = fmaxf(pos, mxs) * invT;

    // bisection for k-th largest on [mn-1e-3, mx]; C(lo) > k >= C(hi)
    float lo = mn - 1e-3f, hi = mx;
    int c_hi = 0;
    const bool need = (cnt > k);
    if (need) {
        for (int it = 0; it < 12; ++it) {
            float mid = 0.5f * (lo + hi);
            int c = 0;
#pragma unroll
            for (int q = 0; q < 8; ++q)
#pragma unroll
                for (int s = 0; s < 8; ++s)
                    c += (int)__popcll(__ballot((float)xv[q][s] > mid));
            if (c > k) lo = mid; else { hi = mid; c_hi = c; }
        }
    }

    // exp sum; boundary bin (lo, hi] apportioned; sentinels (-2) always below lo
    float shi = 0.f, st = 0.f; int nt = 0;
#pragma unroll
    for (int q = 0; q < 8; ++q)
#pragma unroll
        for (int s = 0; s < 8; ++s) {
            float x = (float)xv[q][s];
            float ev = __expf(x * invT - ml);
            if (!need)       { if (x > -1.5f) shi += ev; }
            else if (x > hi) { shi += ev; }
            else if (x > lo) { st += ev; nt++; }
        }
#pragma unroll
    for (int o = 32; o > 0; o >>= 1) {
        shi += __shfl_xor(shi, o, 64);
        st  += __shfl_xor(st,  o, 64);
        nt  += __shfl_xor(nt,  o, 64);
    }
    if (lane == 0) {
        float S = __expf(pos * invT - ml) + shi;
        if (need && c_hi < k && nt > 0)
            S += st * (float)(k - c_hi) / (float)nt;
        g_rowloss[row_id] = (logf(S) + ml) - pos * invT;
    }
}

// ---------- final mean ----------
__global__ __launch_bounds__(256) void loss_kernel(float* __restrict__ out) {
    float s = 0.f;
    for (int i = threadIdx.x; i < Nq; i += 256) s += g_rowloss[i];
    __shared__ float sm[256];
    sm[threadIdx.x] = s; __syncthreads();
    for (int o = 128; o > 0; o >>= 1) {
        if (threadIdx.x < o) sm[threadIdx.x] += sm[threadIdx.x + o];
        __syncthreads();
    }
    if (threadIdx.x == 0) out[0] = sm[0] / (float)Nq;
}

extern "C" void kernel_launch(void* const* d_in, const int* in_sizes, int n_in,
                              void* d_out, int out_size, void* d_ws, size_t ws_size,
                              hipStream_t stream) {
    const float* z         = (const float*)d_in[0];
    const float* query     = (const float*)d_in[3];
    const float* attn_temp = (const float*)d_in[4];
    const float* W         = (const float*)d_in[5];
    const float* bias      = (const float*)d_in[6];
    float* out = (float*)d_out;

    prep_kernel<<<1024 + (Dq * Dq / 4) / 256, 256, 0, stream>>>(z, query, attn_temp, W);
    fw_mfma_kernel<<<dim3(Dq / 128, Nq / 128), 256, 0, stream>>>(bias);
    normalize_kernel<<<Nq / 16, 256, 0, stream>>>();
    sim_mfma_kernel<<<dim3(16, 16), 512, 131072, stream>>>();
    lse_kernel<<<Nq / 4, 256, 0, stream>>>();
    loss_kernel<<<1, 256, 0, stream>>>(out);
}

// Round 12
// 116.297 us; speedup vs baseline: 1.1114x; 1.1114x over previous
//
#include <hip/hip_runtime.h>
#include <hip/hip_bf16.h>
#include <math.h>

#define Bq   2048
#define Cq   8
#define Dq   768
#define NROW 16384      // B*C per half
#define NTOT 32768      // 2*B*C
#define Nq   4096       // 2*B rows of f
#define TEMPq 0.07f
#define NKC  96         // 768/8 k-chunks of 8 bf16 (16 B)

typedef __attribute__((ext_vector_type(8))) short bf16x8;
typedef __attribute__((ext_vector_type(4))) float f32x4;
typedef __attribute__((ext_vector_type(8))) _Float16 f16x8;

// persistent device scratch (fully overwritten every call -> deterministic)
__device__ __hip_bfloat16 g_pooledb[(size_t)Nq * Dq];
__device__ __hip_bfloat16 g_Wb[(size_t)Dq * Dq];
__device__ float          g_f[(size_t)Nq * Dq];
__device__ short          g_fbt[(size_t)NKC * Nq * 8];   // [kc][row][8 bf16] chunk-transposed
__device__ _Float16       g_simh[(size_t)Nq * Nq];
__device__ unsigned int   g_viol;
__device__ float          g_rowloss[Nq];

#define GLDS16(src, dst) __builtin_amdgcn_global_load_lds( \
    (const __attribute__((address_space(1))) void*)(src),  \
    (__attribute__((address_space(3))) void*)(dst), 16, 0, 0)

// ---------- merged: [blocks 0..1023] fused pool, [1024..1599] W->bf16 ----------
__global__ __launch_bounds__(256) void prep_kernel(const float* __restrict__ z,
                                                   const float* __restrict__ query,
                                                   const float* __restrict__ attn_temp,
                                                   const float* __restrict__ W) {
    if (blockIdx.x >= 1024) {
        int i = (blockIdx.x - 1024) * 256 + threadIdx.x;
        if (i == 0) g_viol = 0u;
        float4 v = ((const float4*)W)[i];
        short4 o;
        o.x = ((__hip_bfloat16_raw)__float2bfloat16(v.x)).x;
        o.y = ((__hip_bfloat16_raw)__float2bfloat16(v.y)).x;
        o.z = ((__hip_bfloat16_raw)__float2bfloat16(v.z)).x;
        o.w = ((__hip_bfloat16_raw)__float2bfloat16(v.w)).x;
        ((short4*)g_Wb)[i] = o;
        return;
    }
    int seg  = (int)((blockIdx.x * blockDim.x + threadIdx.x) >> 6);
    int lane = threadIdx.x & 63;
    if (seg >= Nq) return;
    int half = seg >> 11;
    int b    = seg & 2047;
    int baseRow = half * NROW + b * Cq;
    float invt = 1.f / attn_temp[0];

    float4 q4[3];
#pragma unroll
    for (int j = 0; j < 3; ++j) q4[j] = *(const float4*)(query + j * 256 + lane * 4);

    float4 v4[Cq][3];
    float s[Cq];
#pragma unroll
    for (int c = 0; c < Cq; ++c) {
        const float* zr = z + (size_t)(baseRow + c) * Dq;
        float acc = 0.f;
#pragma unroll
        for (int j = 0; j < 3; ++j) {
            float4 vz = *(const float4*)(zr + j * 256 + lane * 4);
            v4[c][j] = vz;
            acc += vz.x * q4[j].x + vz.y * q4[j].y + vz.z * q4[j].z + vz.w * q4[j].w;
        }
#pragma unroll
        for (int o = 32; o > 0; o >>= 1) acc += __shfl_xor(acc, o, 64);
        s[c] = acc * invt;
    }
    float m = s[0];
#pragma unroll
    for (int c = 1; c < Cq; ++c) m = fmaxf(m, s[c]);
    float e[Cq], denom = 0.f;
#pragma unroll
    for (int c = 0; c < Cq; ++c) { e[c] = expf(s[c] - m); denom += e[c]; }
    float inv = 1.f / (denom + 1e-8f);
#pragma unroll
    for (int j = 0; j < 3; ++j) {
        float4 acc = {0.f, 0.f, 0.f, 0.f};
#pragma unroll
        for (int c = 0; c < Cq; ++c) {
            acc.x += v4[c][j].x * e[c];
            acc.y += v4[c][j].y * e[c];
            acc.z += v4[c][j].z * e[c];
            acc.w += v4[c][j].w * e[c];
        }
        short4 o;
        o.x = ((__hip_bfloat16_raw)__float2bfloat16(acc.x * inv)).x;
        o.y = ((__hip_bfloat16_raw)__float2bfloat16(acc.y * inv)).x;
        o.z = ((__hip_bfloat16_raw)__float2bfloat16(acc.z * inv)).x;
        o.w = ((__hip_bfloat16_raw)__float2bfloat16(acc.w * inv)).x;
        *(short4*)((short*)g_pooledb + (size_t)seg * Dq + j * 256 + lane * 4) = o;
    }
}

// ---------- f = pooled @ W^T + b via bf16 MFMA (M=4096, N=768, K=768) ----------
__global__ __launch_bounds__(256) void fw_mfma_kernel(const float* __restrict__ bias) {
    __shared__ short lA[128 * 32];
    __shared__ short lB[128 * 32];
    const int bm = blockIdx.y * 128;
    const int bn = blockIdx.x * 128;

    const int tid  = threadIdx.x;
    const int wave = tid >> 6, lane = tid & 63;
    const int wr = wave >> 1, wc = wave & 1;

    const short* A = (const short*)g_pooledb;
    const short* Bt = (const short*)g_Wb;

    const int c0 = wave * 2, c1 = wave * 2 + 1;
    const int srow = lane >> 2;
    const int scol = (lane & 3) * 8;

    f32x4 acc[4][4];
#pragma unroll
    for (int m = 0; m < 4; ++m)
#pragma unroll
        for (int n = 0; n < 4; ++n) acc[m][n] = (f32x4){0.f, 0.f, 0.f, 0.f};

    for (int k0 = 0; k0 < Dq; k0 += 32) {
        GLDS16(A  + (size_t)(bm + c0 * 16 + srow) * Dq + k0 + scol, lA + c0 * 512);
        GLDS16(A  + (size_t)(bm + c1 * 16 + srow) * Dq + k0 + scol, lA + c1 * 512);
        GLDS16(Bt + (size_t)(bn + c0 * 16 + srow) * Dq + k0 + scol, lB + c0 * 512);
        GLDS16(Bt + (size_t)(bn + c1 * 16 + srow) * Dq + k0 + scol, lB + c1 * 512);
        __syncthreads();

        bf16x8 af[4], bfr[4];
#pragma unroll
        for (int m = 0; m < 4; ++m) {
            int row = wr * 64 + m * 16 + (lane & 15);
            af[m] = *(const bf16x8*)(lA + row * 32 + (lane >> 4) * 8);
        }
#pragma unroll
        for (int n = 0; n < 4; ++n) {
            int row = wc * 64 + n * 16 + (lane & 15);
            bfr[n] = *(const bf16x8*)(lB + row * 32 + (lane >> 4) * 8);
        }
#pragma unroll
        for (int m = 0; m < 4; ++m)
#pragma unroll
            for (int n = 0; n < 4; ++n)
                acc[m][n] = __builtin_amdgcn_mfma_f32_16x16x32_bf16(af[m], bfr[n], acc[m][n], 0, 0, 0);
        __syncthreads();
    }

#pragma unroll
    for (int m = 0; m < 4; ++m) {
        int rowb = bm + wr * 64 + m * 16 + (lane >> 4) * 4;
#pragma unroll
        for (int n = 0; n < 4; ++n) {
            int col = bn + wc * 64 + n * 16 + (lane & 15);
            float bc = bias[col];
#pragma unroll
            for (int j = 0; j < 4; ++j)
                g_f[(size_t)(rowb + j) * Dq + col] = acc[m][n][j] + bc;
        }
    }
}

// ---------- row-normalize -> bf16, chunk-transposed store. 16 rows/block ----------
__global__ __launch_bounds__(256) void normalize_kernel() {
    __shared__ short rowbuf[16][776];
    const int tid = threadIdx.x;
    const int wave = tid >> 6, lane = tid & 63;
    const int r0 = blockIdx.x * 16;

    for (int rr = wave; rr < 16; rr += 4) {
        int row = r0 + rr;
        float v[12];
        float ss = 0.f;
#pragma unroll
        for (int j = 0; j < 12; ++j) { v[j] = g_f[(size_t)row * Dq + j * 64 + lane]; ss += v[j] * v[j]; }
#pragma unroll
        for (int o = 32; o > 0; o >>= 1) ss += __shfl_xor(ss, o, 64);
        float rn = 1.f / sqrtf(ss);
#pragma unroll
        for (int j = 0; j < 12; ++j)
            rowbuf[rr][j * 64 + lane] = ((__hip_bfloat16_raw)__float2bfloat16(v[j] * rn)).x;
    }
    __syncthreads();
#pragma unroll
    for (int i = 0; i < 6; ++i) {
        int idx = i * 256 + tid;
        int ch = idx >> 4;
        int r  = idx & 15;
        bf16x8 val = *(const bf16x8*)&rowbuf[r][ch * 8];
        *(bf16x8*)&g_fbt[((size_t)ch * Nq + r0 + r) * 8] = val;
    }
}

// ---------- sim = fb @ fb^T : 256^2 tile, 8 waves, BK=64, dbuf + counted vmcnt ----------
#define STAGE_SIM(b, kt_) do {                                                          \
    _Pragma("unroll")                                                                   \
    for (int i = 0; i < 4; ++i) {                                                       \
        GLDS16(fbt + ((size_t)((kt_) * 8 + wave) * Nq + bm + i * 64 + lane) * 8,        \
               As + ((b) * 2048 + wave * 256 + i * 64) * 8);                            \
        GLDS16(fbt + ((size_t)((kt_) * 8 + wave) * Nq + bn + i * 64 + lane) * 8,        \
               Bs + ((b) * 2048 + wave * 256 + i * 64) * 8);                            \
    }                                                                                   \
} while (0)

__global__ __launch_bounds__(512) void sim_mfma_kernel() {
    extern __shared__ short smem[];          // 128 KiB
    short* As = smem;
    short* Bs = smem + 32768;

    const int tid  = threadIdx.x;
    const int wave = tid >> 6, lane = tid & 63;
    const int wm = wave >> 2, wn = wave & 3;
    const int bm = blockIdx.y * 256, bn = blockIdx.x * 256;
    const short* fbt = g_fbt;

    f32x4 acc[8][4];
#pragma unroll
    for (int mi = 0; mi < 8; ++mi)
#pragma unroll
        for (int ni = 0; ni < 4; ++ni) acc[mi][ni] = (f32x4){0.f, 0.f, 0.f, 0.f};

    STAGE_SIM(0, 0);

#pragma unroll 1
    for (int kt = 0; kt < 12; ++kt) {
        const int cur = kt & 1;
        if (kt < 11) {
            STAGE_SIM(cur ^ 1, kt + 1);
            asm volatile("s_waitcnt vmcnt(8)" ::: "memory");
        } else {
            asm volatile("s_waitcnt vmcnt(0)" ::: "memory");
        }
        __builtin_amdgcn_s_barrier();
        __builtin_amdgcn_sched_barrier(0);

#pragma unroll
        for (int ks = 0; ks < 2; ++ks) {
            bf16x8 af[8], bfr[4];
            const int kc = (ks * 4 + (lane >> 4)) * 256;
#pragma unroll
            for (int mi = 0; mi < 8; ++mi)
                af[mi] = *(const bf16x8*)(As + (cur * 2048 + kc + wm * 128 + mi * 16 + (lane & 15)) * 8);
#pragma unroll
            for (int ni = 0; ni < 4; ++ni)
                bfr[ni] = *(const bf16x8*)(Bs + (cur * 2048 + kc + wn * 64 + ni * 16 + (lane & 15)) * 8);
            __builtin_amdgcn_s_setprio(1);
#pragma unroll
            for (int mi = 0; mi < 8; ++mi)
#pragma unroll
                for (int ni = 0; ni < 4; ++ni)
                    acc[mi][ni] = __builtin_amdgcn_mfma_f32_16x16x32_bf16(af[mi], bfr[ni], acc[mi][ni], 0, 0, 0);
            __builtin_amdgcn_s_setprio(0);
        }
        __builtin_amdgcn_sched_barrier(0);
        __builtin_amdgcn_s_barrier();
    }

    // epilogue: fp16 store (full matrix, no mirror) + violation count
    int vio = 0;
#pragma unroll
    for (int mi = 0; mi < 8; ++mi) {
        int rowb = bm + wm * 128 + mi * 16 + (lane >> 4) * 4;
#pragma unroll
        for (int ni = 0; ni < 4; ++ni) {
            int col = bn + wn * 64 + ni * 16 + (lane & 15);
#pragma unroll
            for (int j = 0; j < 4; ++j) {
                float x = acc[mi][ni][j];
                g_simh[(size_t)(rowb + j) * Nq + col] = (_Float16)x;
                vio += (x > 0.9f) && ((((rowb + j) ^ col) & 2047) != 0);
            }
        }
    }
#pragma unroll
    for (int o = 32; o > 0; o >>= 1) vio += __shfl_xor(vio, o, 64);
    if (lane == 0 && vio > 0) atomicAdd(&g_viol, (unsigned int)vio);
}

// ---------- per-row top-k logsumexp: one wave per row, ballot-popcount bisection ----------
__global__ __launch_bounds__(256) void lse_kernel() {
    const int row_id = (int)((blockIdx.x * blockDim.x + threadIdx.x) >> 6);
    const int lane = threadIdx.x & 63;
    const _Float16* row = g_simh + (size_t)row_id * Nq;
    const int labi = row_id & 2047;
    const float invT = 1.0f / TEMPq;

    long long total = (long long)Nq * 4094LL - (long long)g_viol;
    int k = (int)(total / 8192LL);
    if (k < 1) k = 1;

    float v[64];
    float mx = -1e30f, mn = 1e30f;
    int cnt = 0;
#pragma unroll
    for (int q = 0; q < 8; ++q) {
        int j0 = q * 512 + lane * 8;
        f16x8 x8 = *(const f16x8*)(row + j0);
#pragma unroll
        for (int s = 0; s < 8; ++s) {
            int jj = q * 8 + s;
            int j  = j0 + s;
            float xv = (float)x8[s];
            bool sf = (xv <= 0.9f) && (((j ^ labi) & 2047) != 0);
            float val = sf ? xv : -2.0f;
            v[jj] = val;
            mx = fmaxf(mx, val);
            mn = fminf(mn, sf ? xv : 2.0f);
            cnt += (int)__popcll(__ballot(sf));
        }
    }
#pragma unroll
    for (int o = 32; o > 0; o >>= 1) {
        mx = fmaxf(mx, __shfl_xor(mx, o, 64));
        mn = fminf(mn, __shfl_xor(mn, o, 64));
    }

    const float pos = (float)row[(row_id + Bq) & (Nq - 1)];
    const float mxs = (cnt > 0) ? mx : -10.0f;
    const float ml  = fmaxf(pos, mxs) * invT;

    float lo = mn - 1e-3f, hi = mx;
    int c_hi = 0;
    const bool need = (cnt > k);
    if (need) {
        for (int it = 0; it < 12; ++it) {
            float mid = 0.5f * (lo + hi);
            int c = 0;
#pragma unroll
            for (int jj = 0; jj < 64; ++jj)
                c += (int)__popcll(__ballot(v[jj] > mid));
            if (c > k) lo = mid; else { hi = mid; c_hi = c; }
        }
    }

    float shi = 0.f, st = 0.f; int nt = 0;
#pragma unroll
    for (int jj = 0; jj < 64; ++jj) {
        float x = v[jj];
        float ev = __expf(x * invT - ml);
        if (!need)       { if (x > -1.5f) shi += ev; }
        else if (x > hi) { shi += ev; }
        else if (x > lo) { st += ev; nt++; }
    }
#pragma unroll
    for (int o = 32; o > 0; o >>= 1) {
        shi += __shfl_xor(shi, o, 64);
        st  += __shfl_xor(st,  o, 64);
        nt  += __shfl_xor(nt,  o, 64);
    }
    if (lane == 0) {
        float S = __expf(pos * invT - ml) + shi;
        if (need && c_hi < k && nt > 0)
            S += st * (float)(k - c_hi) / (float)nt;
        g_rowloss[row_id] = (logf(S) + ml) - pos * invT;
    }
}

// ---------- final mean ----------
__global__ __launch_bounds__(256) void loss_kernel(float* __restrict__ out) {
    float s = 0.f;
    for (int i = threadIdx.x; i < Nq; i += 256) s += g_rowloss[i];
    __shared__ float sm[256];
    sm[threadIdx.x] = s; __syncthreads();
    for (int o = 128; o > 0; o >>= 1) {
        if (threadIdx.x < o) sm[threadIdx.x] += sm[threadIdx.x + o];
        __syncthreads();
    }
    if (threadIdx.x == 0) out[0] = sm[0] / (float)Nq;
}

extern "C" void kernel_launch(void* const* d_in, const int* in_sizes, int n_in,
                              void* d_out, int out_size, void* d_ws, size_t ws_size,
                              hipStream_t stream) {
    const float* z         = (const float*)d_in[0];
    const float* query     = (const float*)d_in[3];
    const float* attn_temp = (const float*)d_in[4];
    const float* W         = (const float*)d_in[5];
    const float* bias      = (const float*)d_in[6];
    float* out = (float*)d_out;

    prep_kernel<<<1024 + (Dq * Dq / 4) / 256, 256, 0, stream>>>(z, query, attn_temp, W);
    fw_mfma_kernel<<<dim3(Dq / 128, Nq / 128), 256, 0, stream>>>(bias);
    normalize_kernel<<<Nq / 16, 256, 0, stream>>>();
    sim_mfma_kernel<<<dim3(16, 16), 512, 131072, stream>>>();
    lse_kernel<<<Nq / 4, 256, 0, stream>>>();
    loss_kernel<<<1, 256, 0, stream>>>(out);
}